// Round 2
// baseline (4030.017 us; speedup 1.0000x reference)
//
#include <hip/hip_runtime.h>
#include <hip/hip_bf16.h>
#include <math.h>

#define BB 4
#define CC 64
#define HH 128
#define WW 128
#define FF 6
#define DD 512
#define NHH 128
#define HWSZ (HH*WW)

typedef unsigned short u16;
typedef __attribute__((ext_vector_type(4))) unsigned short u16x4;

__device__ inline float b2f(u16 u){
  union { unsigned int i; float f; } v; v.i = ((unsigned int)u) << 16; return v.f;
}
__device__ inline u16 f2b(float f){
  union { float f; unsigned int i; } v; v.f = f;
  unsigned int r = v.i + 0x7fffu + ((v.i >> 16) & 1u);
  return (u16)(r >> 16);
}

// ---------------- K1: labels from one-hot segmap (last nonzero wins) --------
__global__ void k_labels(const float* __restrict__ seg, int* __restrict__ lab){
  int i = blockIdx.x * 256 + threadIdx.x;          // 0..B*H*W-1
  int b = i >> 14; int hw = i & 16383;
  int l = -1;
  #pragma unroll
  for (int j = 0; j < FF; j++){
    float v = seg[(b*FF + j)*HWSZ + hw];
    if (v != 0.f) l = j;
  }
  lab[i] = l;
}

// ---------------- K2: instance-norm stats over (H,W) per (b,c) --------------
__global__ void k_stats(const float* __restrict__ x, const float* __restrict__ noise,
                        const float* __restrict__ nvar, float* __restrict__ mu,
                        float* __restrict__ rs){
  int bc = blockIdx.x; int b = bc >> 6; int c = bc & 63;
  float nv = nvar[c];
  const float* xp = x + (size_t)bc * HWSZ;
  const float* nz = noise + b * HWSZ;              // noise[b,w,h,0] at w*128+h
  float s = 0.f, ss = 0.f;
  for (int i = threadIdx.x; i < HWSZ; i += 256){
    int h = i >> 7, w = i & 127;
    float v = xp[i] + nz[w*128 + h] * nv;
    s += v; ss += v*v;
  }
  __shared__ float r1[256], r2[256];
  r1[threadIdx.x] = s; r2[threadIdx.x] = ss; __syncthreads();
  for (int st = 128; st > 0; st >>= 1){
    if (threadIdx.x < st){ r1[threadIdx.x] += r1[threadIdx.x+st]; r2[threadIdx.x] += r2[threadIdx.x+st]; }
    __syncthreads();
  }
  if (threadIdx.x == 0){
    float m = r1[0] / (float)HWSZ;
    float var = r2[0] / (float)HWSZ - m*m;
    mu[bc] = m; rs[bc] = rsqrtf(var + 1e-5f);
  }
}

// ---------------- K3: middle_mu[b,f,o] = relu(codes . fc_w[f,o,:] + b) ------
__global__ void k_mm(const float* __restrict__ codes, const float* __restrict__ fcw,
                     const float* __restrict__ fcb, float* __restrict__ mm){
  int bf = blockIdx.x;                              // b*F+f
  int f = bf % FF;
  __shared__ float sc[DD];
  sc[threadIdx.x] = codes[bf*DD + threadIdx.x];     // 512 threads
  __syncthreads();
  int o = threadIdx.x;
  const float* wr = fcw + ((size_t)(f*DD + o)) * DD;
  float acc = fcb[f*DD + o];
  #pragma unroll 8
  for (int d = 0; d < DD; d++) acc += sc[d] * wr[d];
  mm[bf*DD + o] = fmaxf(acc, 0.f);
}

// ---------------- K4: P[b,f,c,kk] = sum_d mm[b,f,d]*w[c,d,kk] (both convs) --
__global__ void k_p(const float* __restrict__ mm, const float* __restrict__ wg,
                    const float* __restrict__ wb, float* __restrict__ Pg,
                    float* __restrict__ Pb){
  int blk = blockIdx.x;                             // (b*F+f)*C + c
  int c = blk % CC; int bf = blk / CC;
  __shared__ float smm[DD];
  for (int i = threadIdx.x; i < DD; i += 256) smm[i] = mm[bf*DD + i];
  __syncthreads();
  __shared__ float red[256];
  const float* wgc = wg + (size_t)c * DD * 9;
  const float* wbc = wb + (size_t)c * DD * 9;
  for (int kk = 0; kk < 9; kk++){
    float ag = 0.f, ab = 0.f;
    for (int d = threadIdx.x; d < DD; d += 256){
      float m = smm[d];
      ag += m * wgc[d*9 + kk];
      ab += m * wbc[d*9 + kk];
    }
    red[threadIdx.x] = ag; __syncthreads();
    for (int st = 128; st > 0; st >>= 1){ if (threadIdx.x < st) red[threadIdx.x] += red[threadIdx.x+st]; __syncthreads(); }
    if (threadIdx.x == 0) Pg[blk*9 + kk] = red[0];
    __syncthreads();
    red[threadIdx.x] = ab; __syncthreads();
    for (int st = 128; st > 0; st >>= 1){ if (threadIdx.x < st) red[threadIdx.x] += red[threadIdx.x+st]; __syncthreads(); }
    if (threadIdx.x == 0) Pb[blk*9 + kk] = red[0];
    __syncthreads();
  }
}

// ---------------- K5: actv = relu(conv3x3(mask)), stored NHWC bf16 ----------
__global__ void k_actv(const float* __restrict__ mask, const float* __restrict__ w,
                       const float* __restrict__ bias, u16* __restrict__ actv){
  int bh = blockIdx.x;                              // b*H + h
  int b = bh >> 7; int h = bh & 127;
  int tw = threadIdx.x;                             // 128 threads = w
  float mreg[3][3][3];
  #pragma unroll
  for (int ci = 0; ci < 3; ci++)
    #pragma unroll
    for (int r = 0; r < 3; r++){
      int hh = h - 1 + r;
      #pragma unroll
      for (int dx = 0; dx < 3; dx++){
        int ww2 = tw - 1 + dx;
        mreg[ci][r][dx] = (hh >= 0 && hh < HH && ww2 >= 0 && ww2 < WW)
                          ? mask[((b*3 + ci)*HH + hh)*WW + ww2] : 0.f;
      }
    }
  __shared__ float sw[NHH*27];
  for (int i = threadIdx.x; i < NHH*27; i += 128) sw[i] = w[i];
  __shared__ float sb[NHH];
  sb[threadIdx.x] = bias[threadIdx.x];
  __syncthreads();
  u16* outp = actv + ((size_t)bh * WW + tw) * NHH;
  for (int n0 = 0; n0 < NHH; n0 += 4){
    u16x4 pkt;
    #pragma unroll
    for (int j = 0; j < 4; j++){
      int n = n0 + j;
      float acc = sb[n];
      const float* wn = &sw[n*27];
      #pragma unroll
      for (int ci = 0; ci < 3; ci++)
        #pragma unroll
        for (int r = 0; r < 3; r++)
          #pragma unroll
          for (int dx = 0; dx < 3; dx++)
            acc += mreg[ci][r][dx] * wn[ci*9 + r*3 + dx];
      pkt[j] = f2b(fmaxf(acc, 0.f));
    }
    *(u16x4*)(outp + n0) = pkt;
  }
}

// ---------------- K6: fused region-gather + SPADE conv + norm + blend -------
__launch_bounds__(128)
__global__ void k_final(const float* __restrict__ x, const float* __restrict__ noise,
    const float* __restrict__ nvar, const int* __restrict__ lab,
    const float* __restrict__ mu, const float* __restrict__ rs,
    const float* __restrict__ Pg, const float* __restrict__ Pb,
    const float* __restrict__ cgb, const float* __restrict__ cbb,
    const u16* __restrict__ actv, const float* __restrict__ sgw,
    const float* __restrict__ sbw, const float* __restrict__ sgb,
    const float* __restrict__ sbb, const float* __restrict__ blg,
    const float* __restrict__ blb, float* __restrict__ out)
{
  int blk = blockIdx.x;                             // ((b*C)+c)*H + h
  int h = blk & 127; int bc = blk >> 7; int c = bc & 63; int b = bc >> 6;
  int tw = threadIdx.x;

  __shared__ __align__(16) float sWg[NHH*12];
  __shared__ __align__(16) float sWb[NHH*12];
  __shared__ float sPg[54], sPb[54];
  __shared__ int sLab[384];

  for (int i = threadIdx.x; i < NHH*9; i += 128){
    int n = i / 9, kk = i - n*9;
    sWg[n*12 + kk] = sgw[(size_t)c*NHH*9 + i];
    sWb[n*12 + kk] = sbw[(size_t)c*NHH*9 + i];
  }
  if (threadIdx.x < 54){
    int f = threadIdx.x / 9, kk = threadIdx.x - f*9;
    sPg[threadIdx.x] = Pg[((b*FF + f)*CC + c)*9 + kk];
    sPb[threadIdx.x] = Pb[((b*FF + f)*CC + c)*9 + kk];
  }
  for (int i = threadIdx.x; i < 384; i += 128){
    int r = i >> 7, ww2 = i & 127; int hh = h - 1 + r;
    sLab[i] = (hh >= 0 && hh < HH) ? lab[b*HWSZ + hh*WW + ww2] : -1;
  }
  __syncthreads();

  // region conv via P gather
  float gAvg = cgb[c], bAvg = cbb[c];
  #pragma unroll
  for (int r = 0; r < 3; r++){
    #pragma unroll
    for (int dx = 0; dx < 3; dx++){
      int ww2 = tw - 1 + dx;
      if (ww2 >= 0 && ww2 < WW){
        int l = sLab[(r << 7) + ww2];
        if (l >= 0){
          gAvg += sPg[l*9 + r*3 + dx];
          bAvg += sPb[l*9 + r*3 + dx];
        }
      }
    }
  }

  // SPADE conv (direct, NHWC bf16 actv)
  int offs[9];
  #pragma unroll
  for (int r = 0; r < 3; r++){
    #pragma unroll
    for (int dx = 0; dx < 3; dx++){
      int hh = h - 1 + r, ww2 = tw - 1 + dx;
      offs[r*3 + dx] = (hh >= 0 && hh < HH && ww2 >= 0 && ww2 < WW)
                       ? ((hh*WW + ww2) * NHH) : -1;
    }
  }
  const u16* ap = actv + (size_t)b * HWSZ * NHH;
  float gSp = sgb[c], bSp = sbb[c];
  for (int n0 = 0; n0 < NHH; n0 += 4){
    float av[9][4];
    #pragma unroll
    for (int t = 0; t < 9; t++){
      if (offs[t] >= 0){
        u16x4 p = *(const u16x4*)(ap + offs[t] + n0);
        #pragma unroll
        for (int j = 0; j < 4; j++) av[t][j] = b2f(p[j]);
      } else {
        #pragma unroll
        for (int j = 0; j < 4; j++) av[t][j] = 0.f;
      }
    }
    #pragma unroll
    for (int j = 0; j < 4; j++){
      int n = n0 + j;
      const float* wgn = &sWg[n*12];
      const float* wbn = &sWb[n*12];
      #pragma unroll
      for (int t = 0; t < 9; t++){
        gSp += av[t][j] * wgn[t];
        bSp += av[t][j] * wbn[t];
      }
    }
  }

  float sga = 1.f / (1.f + expf(-blg[0]));
  float sba = 1.f / (1.f + expf(-blb[0]));
  float gf = sga * gAvg + (1.f - sga) * gSp;
  float bf = sba * bAvg + (1.f - sba) * bSp;
  int idx = (bc << 14) + (h << 7) + tw;
  float xn = x[idx] + noise[b*HWSZ + (tw << 7) + h] * nvar[c];
  float xnorm = (xn - mu[bc]) * rs[bc];
  out[idx] = xnorm * (1.f + gf) + bf;
}

extern "C" void kernel_launch(void* const* d_in, const int* in_sizes, int n_in,
                              void* d_out, int out_size, void* d_ws, size_t ws_size,
                              hipStream_t stream){
  const float* x     = (const float*)d_in[0];
  const float* seg   = (const float*)d_in[1];
  const float* mask  = (const float*)d_in[2];
  const float* codes = (const float*)d_in[3];
  const float* noise = (const float*)d_in[4];
  const float* nvar  = (const float*)d_in[5];
  const float* fcw   = (const float*)d_in[6];
  const float* fcb   = (const float*)d_in[7];
  const float* cgw   = (const float*)d_in[8];
  const float* cgb   = (const float*)d_in[9];
  const float* cbw   = (const float*)d_in[10];
  const float* cbb   = (const float*)d_in[11];
  const float* ssw   = (const float*)d_in[12];
  const float* ssb   = (const float*)d_in[13];
  const float* sgw   = (const float*)d_in[14];
  const float* sgb   = (const float*)d_in[15];
  const float* sbw   = (const float*)d_in[16];
  const float* sbb   = (const float*)d_in[17];
  const float* blg   = (const float*)d_in[18];
  const float* blb   = (const float*)d_in[19];
  float* out = (float*)d_out;

  char* ws = (char*)d_ws;
  int*   lab  = (int*)ws;                      // 65536 * 4      = 262144
  float* mu   = (float*)(ws + 262144);         // 256 * 4
  float* rs   = (float*)(ws + 263168);         // 256 * 4
  float* mm   = (float*)(ws + 264192);         // 12288 * 4      = 49152
  float* Pg   = (float*)(ws + 313344);         // 13824 * 4      = 55296
  float* Pb   = (float*)(ws + 368640);         // 13824 * 4
  u16*   actv = (u16*)(ws + 423936);           // 8388608 * 2    = 16777216

  k_labels<<<dim3((BB*HWSZ)/256), dim3(256), 0, stream>>>(seg, lab);
  k_stats <<<dim3(BB*CC),        dim3(256), 0, stream>>>(x, noise, nvar, mu, rs);
  k_mm    <<<dim3(BB*FF),        dim3(512), 0, stream>>>(codes, fcw, fcb, mm);
  k_p     <<<dim3(BB*FF*CC),     dim3(256), 0, stream>>>(mm, cgw, cbw, Pg, Pb);
  k_actv  <<<dim3(BB*HH),        dim3(128), 0, stream>>>(mask, ssw, ssb, actv);
  k_final <<<dim3(BB*CC*HH),     dim3(128), 0, stream>>>(
      x, noise, nvar, lab, mu, rs, Pg, Pb, cgb, cbb,
      actv, sgw, sbw, sgb, sbb, blg, blb, out);
}

// Round 5
// 327.121 us; speedup vs baseline: 12.3197x; 12.3197x over previous
//
#include <hip/hip_runtime.h>
#include <hip/hip_bf16.h>
#include <math.h>

#define BB 4
#define CC 64
#define HH 128
#define WW 128
#define FF 6
#define DD 512
#define NHH 128
#define HWSZ (HH*WW)

typedef unsigned short u16;
typedef __attribute__((ext_vector_type(4))) unsigned short u16x4;
typedef __attribute__((ext_vector_type(8))) short short8;   // 8 bf16 = 4 VGPRs
typedef __attribute__((ext_vector_type(4))) float f32x4;

__device__ inline float b2f(u16 u){
  union { unsigned int i; float f; } v; v.i = ((unsigned int)u) << 16; return v.f;
}
__device__ inline u16 f2b(float f){
  union { float f; unsigned int i; } v; v.f = f;
  unsigned int r = v.i + 0x7fffu + ((v.i >> 16) & 1u);
  return (u16)(r >> 16);
}

// ---------------- K1: labels from one-hot segmap (last nonzero wins) --------
__global__ void k_labels(const float* __restrict__ seg, int* __restrict__ lab){
  int i = blockIdx.x * 256 + threadIdx.x;
  int b = i >> 14; int hw = i & 16383;
  int l = -1;
  #pragma unroll
  for (int j = 0; j < FF; j++){
    float v = seg[(b*FF + j)*HWSZ + hw];
    if (v != 0.f) l = j;
  }
  lab[i] = l;
}

// ---------------- K2: instance-norm stats over (H,W) per (b,c) --------------
__global__ void k_stats(const float* __restrict__ x, const float* __restrict__ noise,
                        const float* __restrict__ nvar, float* __restrict__ mu,
                        float* __restrict__ rs){
  int bc = blockIdx.x; int b = bc >> 6; int c = bc & 63;
  float nv = nvar[c];
  const float* xp = x + (size_t)bc * HWSZ;
  const float* nz = noise + b * HWSZ;
  float s = 0.f, ss = 0.f;
  for (int i = threadIdx.x; i < HWSZ; i += 256){
    int h = i >> 7, w = i & 127;
    float v = xp[i] + nz[w*128 + h] * nv;
    s += v; ss += v*v;
  }
  __shared__ float r1[256], r2[256];
  r1[threadIdx.x] = s; r2[threadIdx.x] = ss; __syncthreads();
  for (int st = 128; st > 0; st >>= 1){
    if (threadIdx.x < st){ r1[threadIdx.x] += r1[threadIdx.x+st]; r2[threadIdx.x] += r2[threadIdx.x+st]; }
    __syncthreads();
  }
  if (threadIdx.x == 0){
    float m = r1[0] / (float)HWSZ;
    float var = r2[0] / (float)HWSZ - m*m;
    mu[bc] = m; rs[bc] = rsqrtf(var + 1e-5f);
  }
}

// ---------------- K3: middle_mu[b,f,o] = relu(codes . fc_w[f,o,:] + b) ------
__global__ void k_mm(const float* __restrict__ codes, const float* __restrict__ fcw,
                     const float* __restrict__ fcb, float* __restrict__ mm){
  int bf = blockIdx.x;
  int f = bf % FF;
  __shared__ float sc[DD];
  sc[threadIdx.x] = codes[bf*DD + threadIdx.x];
  __syncthreads();
  int o = threadIdx.x;
  const float* wr = fcw + ((size_t)(f*DD + o)) * DD;
  float acc = fcb[f*DD + o];
  #pragma unroll 8
  for (int d = 0; d < DD; d++) acc += sc[d] * wr[d];
  mm[bf*DD + o] = fmaxf(acc, 0.f);
}

// ---------------- K4: P[b,f,c,kk] = sum_d mm[b,f,d]*w[c,d,kk] ---------------
__global__ void k_p(const float* __restrict__ mm, const float* __restrict__ wg,
                    const float* __restrict__ wb, float* __restrict__ Pg,
                    float* __restrict__ Pb){
  int blk = blockIdx.x;
  int c = blk % CC; int bf = blk / CC;
  __shared__ float smm[DD];
  for (int i = threadIdx.x; i < DD; i += 256) smm[i] = mm[bf*DD + i];
  __syncthreads();
  __shared__ float red[256];
  const float* wgc = wg + (size_t)c * DD * 9;
  const float* wbc = wb + (size_t)c * DD * 9;
  for (int kk = 0; kk < 9; kk++){
    float ag = 0.f, ab = 0.f;
    for (int d = threadIdx.x; d < DD; d += 256){
      float m = smm[d];
      ag += m * wgc[d*9 + kk];
      ab += m * wbc[d*9 + kk];
    }
    red[threadIdx.x] = ag; __syncthreads();
    for (int st = 128; st > 0; st >>= 1){ if (threadIdx.x < st) red[threadIdx.x] += red[threadIdx.x+st]; __syncthreads(); }
    if (threadIdx.x == 0) Pg[blk*9 + kk] = red[0];
    __syncthreads();
    red[threadIdx.x] = ab; __syncthreads();
    for (int st = 128; st > 0; st >>= 1){ if (threadIdx.x < st) red[threadIdx.x] += red[threadIdx.x+st]; __syncthreads(); }
    if (threadIdx.x == 0) Pb[blk*9 + kk] = red[0];
    __syncthreads();
  }
}

// ---------------- K5: actv = relu(conv3x3(mask)), stored NHWC bf16 ----------
__global__ void k_actv(const float* __restrict__ mask, const float* __restrict__ w,
                       const float* __restrict__ bias, u16* __restrict__ actv){
  int bh = blockIdx.x;
  int b = bh >> 7; int h = bh & 127;
  int tw = threadIdx.x;
  float mreg[3][3][3];
  #pragma unroll
  for (int ci = 0; ci < 3; ci++)
    #pragma unroll
    for (int r = 0; r < 3; r++){
      int hh = h - 1 + r;
      #pragma unroll
      for (int dx = 0; dx < 3; dx++){
        int ww2 = tw - 1 + dx;
        mreg[ci][r][dx] = (hh >= 0 && hh < HH && ww2 >= 0 && ww2 < WW)
                          ? mask[((b*3 + ci)*HH + hh)*WW + ww2] : 0.f;
      }
    }
  __shared__ float sw[NHH*27];
  for (int i = threadIdx.x; i < NHH*27; i += 128) sw[i] = w[i];
  __shared__ float sb[NHH];
  sb[threadIdx.x] = bias[threadIdx.x];
  __syncthreads();
  u16* outp = actv + ((size_t)bh * WW + tw) * NHH;
  for (int n0 = 0; n0 < NHH; n0 += 4){
    u16x4 pkt;
    #pragma unroll
    for (int j = 0; j < 4; j++){
      int n = n0 + j;
      float acc = sb[n];
      const float* wn = &sw[n*27];
      #pragma unroll
      for (int ci = 0; ci < 3; ci++)
        #pragma unroll
        for (int r = 0; r < 3; r++)
          #pragma unroll
          for (int dx = 0; dx < 3; dx++)
            acc += mreg[ci][r][dx] * wn[ci*9 + r*3 + dx];
      pkt[j] = f2b(fmaxf(acc, 0.f));
    }
    *(u16x4*)(outp + n0) = pkt;
  }
}

// ---------------- K5b: BwT[j][k] bf16, k = tap*128 + n ----------------------
// j<64: gamma weights sgw[c=j][n][tap]; j>=64: beta weights sbw[c=j-64][n][tap]
__global__ void k_bw(const float* __restrict__ sgw, const float* __restrict__ sbw,
                     u16* __restrict__ BwT){
  int idx = blockIdx.x*256 + threadIdx.x;          // 128*1152 = 147456
  int j = idx / 1152, k = idx - j*1152;
  int tap = k >> 7, n = k & 127;
  float v = (j < 64) ? sgw[(j*NHH + n)*9 + tap] : sbw[((j-64)*NHH + n)*9 + tap];
  BwT[idx] = f2b(v);
}

// ---------------- K6: SPADE convs as MFMA GEMM ------------------------------
// Per (b,h) row: out[128 pixels][128 j] = A[128][1152] x B[1152][128]
// A = im2col of NHWC actv (shifted contiguous reads), B = BwT (pre-transposed)
__global__ __launch_bounds__(256) void k_spade(const u16* __restrict__ actv,
                                               const u16* __restrict__ BwT,
                                               u16* __restrict__ gSp){
  int bh = blockIdx.x; int b = bh >> 7; int h = bh & 127;
  __shared__ __align__(16) u16 Ash[128*72];        // [pixel][64k + 8 pad]
  __shared__ __align__(16) u16 Bsh[128*72];        // [j][64k + 8 pad]
  int tid = threadIdx.x;
  int wid = tid >> 6, lane = tid & 63;
  int wr = wid >> 1, wc = wid & 1;                 // 2x2 wave grid, 64x64 each
  int l15 = lane & 15, lhi = lane >> 4;

  f32x4 acc[4][4];
  #pragma unroll
  for (int mi = 0; mi < 4; mi++)
    #pragma unroll
    for (int ni = 0; ni < 4; ni++) acc[mi][ni] = 0.f;

  const u16* ab = actv + (size_t)b * HWSZ * NHH;

  for (int kt = 0; kt < 18; kt++){                 // K=1152 in BK=64 steps
    int tap = kt >> 1, n0 = (kt & 1) << 6;
    int r = tap / 3, dx = tap - r*3;
    int h2 = h - 1 + r;
    bool hok = (h2 >= 0) && (h2 < HH);
    // stage A: 128 pixels x 64 ch, zero-filled at borders
    for (int i = tid; i < 1024; i += 256){
      int pix = i >> 3, cp = i & 7;
      int w2 = pix - 1 + dx;
      short8 v = 0;
      if (hok && w2 >= 0 && w2 < WW)
        v = *(const short8*)(ab + (((size_t)h2*WW + w2)*NHH + n0 + cp*8));
      *(short8*)&Ash[pix*72 + cp*8] = v;
    }
    // stage B: 128 j x 64 k
    for (int i = tid; i < 1024; i += 256){
      int n = i >> 3, cp = i & 7;
      *(short8*)&Bsh[n*72 + cp*8] = *(const short8*)(BwT + (size_t)n*1152 + kt*64 + cp*8);
    }
    __syncthreads();
    short8 af[4][2], bfr[2][4];
    #pragma unroll
    for (int mi = 0; mi < 4; mi++)
      #pragma unroll
      for (int ks = 0; ks < 2; ks++)
        af[mi][ks] = *(const short8*)&Ash[(wr*64 + mi*16 + l15)*72 + ks*32 + lhi*8];
    #pragma unroll
    for (int ks = 0; ks < 2; ks++)
      #pragma unroll
      for (int ni = 0; ni < 4; ni++)
        bfr[ks][ni] = *(const short8*)&Bsh[(wc*64 + ni*16 + l15)*72 + ks*32 + lhi*8];
    #pragma unroll
    for (int mi = 0; mi < 4; mi++)
      #pragma unroll
      for (int ni = 0; ni < 4; ni++)
        #pragma unroll
        for (int ks = 0; ks < 2; ks++)
          acc[mi][ni] = __builtin_amdgcn_mfma_f32_16x16x32_bf16(
              af[mi][ks], bfr[ks][ni], acc[mi][ni], 0, 0, 0);
    __syncthreads();
  }

  // epilogue: gSp[b][h][j][w] bf16, 8B packed stores (4 consecutive w per lane)
  size_t obase = (size_t)bh * (128*128);
  #pragma unroll
  for (int mi = 0; mi < 4; mi++){
    int w0 = wr*64 + mi*16 + lhi*4;
    #pragma unroll
    for (int ni = 0; ni < 4; ni++){
      int j = wc*64 + ni*16 + l15;
      u16x4 pkt;
      #pragma unroll
      for (int q = 0; q < 4; q++) pkt[q] = f2b(acc[mi][ni][q]);
      *(u16x4*)(gSp + obase + (size_t)j*128 + w0) = pkt;
    }
  }
}

// ---------------- K7: region-gather + norm + blend (elementwise) ------------
__launch_bounds__(128)
__global__ void k_out(const float* __restrict__ x, const float* __restrict__ noise,
    const float* __restrict__ nvar, const int* __restrict__ lab,
    const float* __restrict__ mu, const float* __restrict__ rs,
    const float* __restrict__ Pg, const float* __restrict__ Pb,
    const float* __restrict__ cgb, const float* __restrict__ cbb,
    const u16* __restrict__ gSp, const float* __restrict__ sgb,
    const float* __restrict__ sbb, const float* __restrict__ blg,
    const float* __restrict__ blb, float* __restrict__ out)
{
  int blk = blockIdx.x;                            // ((b*C)+c)*H + h
  int h = blk & 127; int bc = blk >> 7; int c = bc & 63; int b = bc >> 6;
  int tw = threadIdx.x;

  __shared__ float sPg[54], sPb[54];
  __shared__ int sLab[384];
  if (threadIdx.x < 54){
    int f = threadIdx.x / 9, kk = threadIdx.x - f*9;
    sPg[threadIdx.x] = Pg[((b*FF + f)*CC + c)*9 + kk];
    sPb[threadIdx.x] = Pb[((b*FF + f)*CC + c)*9 + kk];
  }
  for (int i = threadIdx.x; i < 384; i += 128){
    int r = i >> 7, ww2 = i & 127; int hh = h - 1 + r;
    sLab[i] = (hh >= 0 && hh < HH) ? lab[b*HWSZ + hh*WW + ww2] : -1;
  }
  __syncthreads();

  float gAvg = cgb[c], bAvg = cbb[c];
  #pragma unroll
  for (int r = 0; r < 3; r++){
    #pragma unroll
    for (int dx = 0; dx < 3; dx++){
      int ww2 = tw - 1 + dx;
      if (ww2 >= 0 && ww2 < WW){
        int l = sLab[(r << 7) + ww2];
        if (l >= 0){
          gAvg += sPg[l*9 + r*3 + dx];
          bAvg += sPb[l*9 + r*3 + dx];
        }
      }
    }
  }

  size_t sbase = ((size_t)(b*HH + h)) * (128*128);
  float gSpv = b2f(gSp[sbase + (size_t)c*128 + tw]) + sgb[c];
  float bSpv = b2f(gSp[sbase + (size_t)(64 + c)*128 + tw]) + sbb[c];

  float sga = 1.f / (1.f + expf(-blg[0]));
  float sba = 1.f / (1.f + expf(-blb[0]));
  float gf = sga * gAvg + (1.f - sga) * gSpv;
  float bf = sba * bAvg + (1.f - sba) * bSpv;
  int idx = (bc << 14) + (h << 7) + tw;
  float xn = x[idx] + noise[b*HWSZ + (tw << 7) + h] * nvar[c];
  float xnorm = (xn - mu[bc]) * rs[bc];
  out[idx] = xnorm * (1.f + gf) + bf;
}

extern "C" void kernel_launch(void* const* d_in, const int* in_sizes, int n_in,
                              void* d_out, int out_size, void* d_ws, size_t ws_size,
                              hipStream_t stream){
  const float* x     = (const float*)d_in[0];
  const float* seg   = (const float*)d_in[1];
  const float* mask  = (const float*)d_in[2];
  const float* codes = (const float*)d_in[3];
  const float* noise = (const float*)d_in[4];
  const float* nvar  = (const float*)d_in[5];
  const float* fcw   = (const float*)d_in[6];
  const float* fcb   = (const float*)d_in[7];
  const float* cgw   = (const float*)d_in[8];
  const float* cgb   = (const float*)d_in[9];
  const float* cbw   = (const float*)d_in[10];
  const float* cbb   = (const float*)d_in[11];
  const float* ssw   = (const float*)d_in[12];
  const float* ssb   = (const float*)d_in[13];
  const float* sgw   = (const float*)d_in[14];
  const float* sgb   = (const float*)d_in[15];
  const float* sbw   = (const float*)d_in[16];
  const float* sbb   = (const float*)d_in[17];
  const float* blg   = (const float*)d_in[18];
  const float* blb   = (const float*)d_in[19];
  float* out = (float*)d_out;

  char* ws = (char*)d_ws;
  int*   lab  = (int*)ws;                       // 262144 B
  float* mu   = (float*)(ws + 262144);          // 1024
  float* rs   = (float*)(ws + 263168);          // 1024
  float* mm   = (float*)(ws + 264192);          // 49152
  float* Pg   = (float*)(ws + 313344);          // 55296
  float* Pb   = (float*)(ws + 368640);          // 55296
  u16*   BwT  = (u16*)(ws + 423936);            // 294912
  u16*   actv = (u16*)(ws + 718848);            // 16777216
  u16*   gSp  = (u16*)(ws + 17496064);          // 16777216  (end ~34.3 MB)

  k_labels<<<dim3((BB*HWSZ)/256), dim3(256), 0, stream>>>(seg, lab);
  k_stats <<<dim3(BB*CC),        dim3(256), 0, stream>>>(x, noise, nvar, mu, rs);
  k_mm    <<<dim3(BB*FF),        dim3(512), 0, stream>>>(codes, fcw, fcb, mm);
  k_p     <<<dim3(BB*FF*CC),     dim3(256), 0, stream>>>(mm, cgw, cbw, Pg, Pb);
  k_bw    <<<dim3(576),          dim3(256), 0, stream>>>(sgw, sbw, BwT);
  k_actv  <<<dim3(BB*HH),        dim3(128), 0, stream>>>(mask, ssw, ssb, actv);
  k_spade <<<dim3(BB*HH),        dim3(256), 0, stream>>>(actv, BwT, gSp);
  k_out   <<<dim3(BB*CC*HH),     dim3(128), 0, stream>>>(
      x, noise, nvar, lab, mu, rs, Pg, Pb, cgb, cbb,
      gSp, sgb, sbb, blg, blb, out);
}

// Round 6
// 265.080 us; speedup vs baseline: 15.2030x; 1.2340x over previous
//
#include <hip/hip_runtime.h>
#include <hip/hip_bf16.h>
#include <math.h>

#define BB 4
#define CC 64
#define HH 128
#define WW 128
#define FF 6
#define DD 512
#define NHH 128
#define HWSZ (HH*WW)

typedef unsigned short u16;
typedef __attribute__((ext_vector_type(4))) unsigned short u16x4;
typedef __attribute__((ext_vector_type(8))) short short8;   // 8 bf16 = 4 VGPRs
typedef __attribute__((ext_vector_type(4))) float f32x4;

__device__ inline float b2f(u16 u){
  union { unsigned int i; float f; } v; v.i = ((unsigned int)u) << 16; return v.f;
}
__device__ inline u16 f2b(float f){
  union { float f; unsigned int i; } v; v.f = f;
  unsigned int r = v.i + 0x7fffu + ((v.i >> 16) & 1u);
  return (u16)(r >> 16);
}

// ---------------- K1: labels from one-hot segmap (last nonzero wins) --------
__global__ void k_labels(const float* __restrict__ seg, int* __restrict__ lab){
  int i = blockIdx.x * 256 + threadIdx.x;
  int b = i >> 14; int hw = i & 16383;
  int l = -1;
  #pragma unroll
  for (int j = 0; j < FF; j++){
    float v = seg[(b*FF + j)*HWSZ + hw];
    if (v != 0.f) l = j;
  }
  lab[i] = l;
}

// ---------------- K1b: noise transpose nzT[b][h][w] = noise[b][w*128+h] -----
__global__ void k_nzT(const float* __restrict__ noise, float* __restrict__ nzT){
  __shared__ float tile[32][33];
  int blk = blockIdx.x;                 // b*16 + tj*4 + ti
  int b = blk >> 4, t = blk & 15;
  int ti = t & 3, tj = t >> 2;
  int h0 = ti*32, w0 = tj*32;
  int tx = threadIdx.x & 31, ty = threadIdx.x >> 5;   // 32x8
  #pragma unroll
  for (int k = 0; k < 4; k++){
    int r = ty + 8*k;
    tile[r][tx] = noise[b*HWSZ + (w0+r)*128 + h0 + tx];
  }
  __syncthreads();
  #pragma unroll
  for (int k = 0; k < 4; k++){
    int r = ty + 8*k;
    nzT[b*HWSZ + (h0+r)*128 + w0 + tx] = tile[tx][r];
  }
}

// ---------------- K2: instance-norm stats (coalesced, float4, shfl) ---------
__global__ void k_stats(const float* __restrict__ x, const float* __restrict__ nzT,
                        const float* __restrict__ nvar, float* __restrict__ mu,
                        float* __restrict__ rs){
  int bc = blockIdx.x; int b = bc >> 6; int c = bc & 63;
  float nv = nvar[c];
  const float4* xp = (const float4*)(x + (size_t)bc * HWSZ);
  const float4* np = (const float4*)(nzT + (size_t)b * HWSZ);
  float s = 0.f, ss = 0.f;
  for (int i = threadIdx.x; i < HWSZ/4; i += 256){
    float4 xv = xp[i], nn = np[i];
    float v0 = xv.x + nn.x*nv, v1 = xv.y + nn.y*nv;
    float v2 = xv.z + nn.z*nv, v3 = xv.w + nn.w*nv;
    s += v0+v1+v2+v3;
    ss += v0*v0 + v1*v1 + v2*v2 + v3*v3;
  }
  #pragma unroll
  for (int off = 32; off; off >>= 1){
    s  += __shfl_down(s, off);
    ss += __shfl_down(ss, off);
  }
  __shared__ float wsum[4], wss[4];
  int wi = threadIdx.x >> 6, lane = threadIdx.x & 63;
  if (lane == 0){ wsum[wi] = s; wss[wi] = ss; }
  __syncthreads();
  if (threadIdx.x == 0){
    float S = wsum[0]+wsum[1]+wsum[2]+wsum[3];
    float SS = wss[0]+wss[1]+wss[2]+wss[3];
    float m = S / (float)HWSZ;
    float var = SS / (float)HWSZ - m*m;
    mu[bc] = m; rs[bc] = rsqrtf(var + 1e-5f);
  }
}

// ---------------- K3: middle_mu, wave-per-o, coalesced, shfl reduce ---------
__global__ __launch_bounds__(256) void k_mm(const float* __restrict__ codes,
                     const float* __restrict__ fcw,
                     const float* __restrict__ fcb, float* __restrict__ mm){
  int blk = blockIdx.x;                 // bf*8 + og
  int og = blk & 7, bf = blk >> 3; int f = bf % FF;
  __shared__ float sc[DD];
  int tid = threadIdx.x;
  for (int i = tid; i < DD; i += 256) sc[i] = codes[bf*DD + i];
  __syncthreads();
  int wi = tid >> 6, lane = tid & 63;
  for (int oo = 0; oo < 16; oo += 2){
    int o1 = og*64 + wi*16 + oo, o2 = o1 + 1;
    const float* w1 = fcw + ((size_t)(f*DD + o1)) * DD;
    const float* w2 = w1 + DD;
    float a1 = 0.f, a2 = 0.f;
    #pragma unroll
    for (int k = 0; k < 8; k++){
      int d = lane + k*64;
      float sv = sc[d];
      a1 += sv * w1[d];
      a2 += sv * w2[d];
    }
    #pragma unroll
    for (int off = 32; off; off >>= 1){
      a1 += __shfl_down(a1, off);
      a2 += __shfl_down(a2, off);
    }
    if (lane == 0){
      mm[bf*DD + o1] = fmaxf(a1 + fcb[f*DD + o1], 0.f);
      mm[bf*DD + o2] = fmaxf(a2 + fcb[f*DD + o2], 0.f);
    }
  }
}

// ---------------- K4: P[b][f][t][c] = sum_d mm[b,f,d]*w[c,d,t] --------------
// grid = BB*FF*8; block 576 thr: (ds 0..7) x (c8 0..7) x (t 0..8)
__global__ __launch_bounds__(576) void k_p(const float* __restrict__ mm,
                    const float* __restrict__ wg,
                    const float* __restrict__ wb, float* __restrict__ Pg,
                    float* __restrict__ Pb){
  int blk = blockIdx.x;
  int cg = blk & 7, bf = blk >> 3;
  __shared__ float smm[DD];
  __shared__ float pg[8][72], pb[8][72];
  int tid = threadIdx.x;
  for (int i = tid; i < DD; i += 576) smm[i] = mm[bf*DD + i];
  __syncthreads();
  int ds = tid / 72, rem = tid % 72;
  int c8 = rem / 9, t = rem % 9;
  int c = cg*8 + c8;
  const float* wgp = wg + (size_t)c * DD * 9 + t;
  const float* wbp = wb + (size_t)c * DD * 9 + t;
  float ag = 0.f, ab = 0.f;
  int d0 = ds * 64;
  #pragma unroll 4
  for (int d = d0; d < d0 + 64; d++){
    float m = smm[d];
    ag += m * wgp[d*9];
    ab += m * wbp[d*9];
  }
  pg[ds][rem] = ag; pb[ds][rem] = ab;
  __syncthreads();
  if (tid < 72){
    float sg = 0.f, sb = 0.f;
    #pragma unroll
    for (int k = 0; k < 8; k++){ sg += pg[k][tid]; sb += pb[k][tid]; }
    int cc = cg*8 + tid/9, tt = tid%9;
    Pg[bf*576 + tt*64 + cc] = sg;
    Pb[bf*576 + tt*64 + cc] = sb;
  }
}

// ---------------- K5: actv = relu(conv3x3(mask)), stored NHWC bf16 ----------
__global__ void k_actv(const float* __restrict__ mask, const float* __restrict__ w,
                       const float* __restrict__ bias, u16* __restrict__ actv){
  int bh = blockIdx.x;
  int b = bh >> 7; int h = bh & 127;
  int tw = threadIdx.x;
  float mreg[3][3][3];
  #pragma unroll
  for (int ci = 0; ci < 3; ci++)
    #pragma unroll
    for (int r = 0; r < 3; r++){
      int hh = h - 1 + r;
      #pragma unroll
      for (int dx = 0; dx < 3; dx++){
        int ww2 = tw - 1 + dx;
        mreg[ci][r][dx] = (hh >= 0 && hh < HH && ww2 >= 0 && ww2 < WW)
                          ? mask[((b*3 + ci)*HH + hh)*WW + ww2] : 0.f;
      }
    }
  __shared__ float sw[NHH*27];
  for (int i = threadIdx.x; i < NHH*27; i += 128) sw[i] = w[i];
  __shared__ float sb[NHH];
  sb[threadIdx.x] = bias[threadIdx.x];
  __syncthreads();
  u16* outp = actv + ((size_t)bh * WW + tw) * NHH;
  for (int n0 = 0; n0 < NHH; n0 += 4){
    u16x4 pkt;
    #pragma unroll
    for (int j = 0; j < 4; j++){
      int n = n0 + j;
      float acc = sb[n];
      const float* wn = &sw[n*27];
      #pragma unroll
      for (int ci = 0; ci < 3; ci++)
        #pragma unroll
        for (int r = 0; r < 3; r++)
          #pragma unroll
          for (int dx = 0; dx < 3; dx++)
            acc += mreg[ci][r][dx] * wn[ci*9 + r*3 + dx];
      pkt[j] = f2b(fmaxf(acc, 0.f));
    }
    *(u16x4*)(outp + n0) = pkt;
  }
}

// ---------------- K5b: BwT[j][k] bf16, k = tap*128 + n ----------------------
__global__ void k_bw(const float* __restrict__ sgw, const float* __restrict__ sbw,
                     u16* __restrict__ BwT){
  int idx = blockIdx.x*256 + threadIdx.x;          // 128*1152 = 147456
  int j = idx / 1152, k = idx - j*1152;
  int tap = k >> 7, n = k & 127;
  float v = (j < 64) ? sgw[(j*NHH + n)*9 + tap] : sbw[((j-64)*NHH + n)*9 + tap];
  BwT[idx] = f2b(v);
}

// ---------------- K6: SPADE GEMM + fused region-gather/norm/blend epilogue --
__global__ __launch_bounds__(256, 2) void k_spade(const u16* __restrict__ actv,
    const u16* __restrict__ BwT, const int* __restrict__ lab,
    const float* __restrict__ Pgf, const float* __restrict__ Pbf,
    const float* __restrict__ x, const float* __restrict__ nzT,
    const float* __restrict__ nvar, const float* __restrict__ mu,
    const float* __restrict__ rs,
    const float* __restrict__ cgb, const float* __restrict__ cbb,
    const float* __restrict__ sgb, const float* __restrict__ sbb,
    const float* __restrict__ blg, const float* __restrict__ blb,
    float* __restrict__ out)
{
  int bh = blockIdx.x; int b = bh >> 7; int h = bh & 127;
  // union region: GEMM {Ash,Bsh} then epilogue spGB[128][132] u16
  __shared__ __align__(16) u16 Ub[18432];
  __shared__ float sPg[64*57];
  __shared__ float sPb[64*57];
  __shared__ int sLab[390];
  u16* Ash = Ub;
  u16* Bsh = Ub + 9216;

  int tid = threadIdx.x;
  int wid = tid >> 6, lane = tid & 63;
  int wr = wid >> 1, wc = wid & 1;
  int l15 = lane & 15, lhi = lane >> 4;

  // stage P (per-b, both mats) and labels (3 rows) — independent of Ub;
  // covered by the first in-loop barrier.
  for (int i = tid; i < 3456; i += 256){
    int lt = i >> 6, c = i & 63;
    sPg[c*57 + lt] = Pgf[b*3456 + i];
    sPb[c*57 + lt] = Pbf[b*3456 + i];
  }
  for (int i = tid; i < 390; i += 256){
    int r = i / 130, ww2 = i % 130;
    int hh = h - 1 + r, w2 = ww2 - 1;
    sLab[i] = (hh >= 0 && hh < HH && w2 >= 0 && w2 < WW)
              ? lab[b*HWSZ + hh*WW + w2] : -1;
  }

  f32x4 acc[4][4];
  #pragma unroll
  for (int mi = 0; mi < 4; mi++)
    #pragma unroll
    for (int ni = 0; ni < 4; ni++) acc[mi][ni] = 0.f;

  const u16* ab = actv + (size_t)b * HWSZ * NHH;

  for (int kt = 0; kt < 18; kt++){                 // K=1152 in BK=64 steps
    int tap = kt >> 1, n0 = (kt & 1) << 6;
    int r = tap / 3, dx = tap - r*3;
    int h2 = h - 1 + r;
    bool hok = (h2 >= 0) && (h2 < HH);
    for (int i = tid; i < 1024; i += 256){
      int pix = i >> 3, cp = i & 7;
      int w2 = pix - 1 + dx;
      short8 v = 0;
      if (hok && w2 >= 0 && w2 < WW)
        v = *(const short8*)(ab + (((size_t)h2*WW + w2)*NHH + n0 + cp*8));
      *(short8*)&Ash[pix*72 + cp*8] = v;
    }
    for (int i = tid; i < 1024; i += 256){
      int n = i >> 3, cp = i & 7;
      *(short8*)&Bsh[n*72 + cp*8] = *(const short8*)(BwT + (size_t)n*1152 + kt*64 + cp*8);
    }
    __syncthreads();
    short8 af[4][2], bfr[2][4];
    #pragma unroll
    for (int mi = 0; mi < 4; mi++)
      #pragma unroll
      for (int ks = 0; ks < 2; ks++)
        af[mi][ks] = *(const short8*)&Ash[(wr*64 + mi*16 + l15)*72 + ks*32 + lhi*8];
    #pragma unroll
    for (int ks = 0; ks < 2; ks++)
      #pragma unroll
      for (int ni = 0; ni < 4; ni++)
        bfr[ks][ni] = *(const short8*)&Bsh[(wc*64 + ni*16 + l15)*72 + ks*32 + lhi*8];
    #pragma unroll
    for (int mi = 0; mi < 4; mi++)
      #pragma unroll
      for (int ni = 0; ni < 4; ni++)
        #pragma unroll
        for (int ks = 0; ks < 2; ks++)
          acc[mi][ni] = __builtin_amdgcn_mfma_f32_16x16x32_bf16(
              af[mi][ks], bfr[ks][ni], acc[mi][ni], 0, 0, 0);
    __syncthreads();
  }

  // ---- epilogue phase 1: acc -> LDS spGB[j][132] (bf16) ----
  u16* spGB = Ub;
  #pragma unroll
  for (int mi = 0; mi < 4; mi++){
    int w0 = wr*64 + mi*16 + lhi*4;
    #pragma unroll
    for (int ni = 0; ni < 4; ni++){
      int j = wc*64 + ni*16 + l15;
      u16x4 pkt;
      #pragma unroll
      for (int q = 0; q < 4; q++) pkt[q] = f2b(acc[mi][ni][q]);
      *(u16x4*)&spGB[j*132 + w0] = pkt;
    }
  }
  __syncthreads();

  // ---- epilogue phase 2: region gather + norm + blend, write out ----
  float sga = 1.f / (1.f + expf(-blg[0]));
  float sba = 1.f / (1.f + expf(-blb[0]));
  int w = tid & 127, chalf = tid >> 7;
  float nzv = nzT[b*HWSZ + h*128 + w];
  for (int it = 0; it < 32; it++){
    int c = it*2 + chalf;
    int bc = b*CC + c;
    float g  = b2f(spGB[c*132 + w])        + sgb[c];
    float bt = b2f(spGB[(64 + c)*132 + w]) + sbb[c];
    float gA = cgb[c], bA = cbb[c];
    #pragma unroll
    for (int t = 0; t < 9; t++){
      int r = t/3, dx = t - r*3;
      int l = sLab[r*130 + w + dx];
      if (l >= 0){
        gA += sPg[c*57 + l*9 + t];
        bA += sPb[c*57 + l*9 + t];
      }
    }
    float gf  = sga*gA + (1.f - sga)*g;
    float bfv = sba*bA + (1.f - sba)*bt;
    size_t idx = (size_t)bc*HWSZ + h*128 + w;
    float xn = x[idx] + nzv * nvar[c];
    float xnorm = (xn - mu[bc]) * rs[bc];
    out[idx] = xnorm * (1.f + gf) + bfv;
  }
}

extern "C" void kernel_launch(void* const* d_in, const int* in_sizes, int n_in,
                              void* d_out, int out_size, void* d_ws, size_t ws_size,
                              hipStream_t stream){
  const float* x     = (const float*)d_in[0];
  const float* seg   = (const float*)d_in[1];
  const float* mask  = (const float*)d_in[2];
  const float* codes = (const float*)d_in[3];
  const float* noise = (const float*)d_in[4];
  const float* nvar  = (const float*)d_in[5];
  const float* fcw   = (const float*)d_in[6];
  const float* fcb   = (const float*)d_in[7];
  const float* cgw   = (const float*)d_in[8];
  const float* cgb   = (const float*)d_in[9];
  const float* cbw   = (const float*)d_in[10];
  const float* cbb   = (const float*)d_in[11];
  const float* ssw   = (const float*)d_in[12];
  const float* ssb   = (const float*)d_in[13];
  const float* sgw   = (const float*)d_in[14];
  const float* sgb   = (const float*)d_in[15];
  const float* sbw   = (const float*)d_in[16];
  const float* sbb   = (const float*)d_in[17];
  const float* blg   = (const float*)d_in[18];
  const float* blb   = (const float*)d_in[19];
  float* out = (float*)d_out;

  char* ws = (char*)d_ws;
  int*   lab  = (int*)ws;                       // 262144 B
  float* mu   = (float*)(ws + 262144);          // 1024
  float* rs   = (float*)(ws + 263168);          // 1024
  float* mm   = (float*)(ws + 264192);          // 49152
  float* Pg   = (float*)(ws + 313344);          // 55296
  float* Pb   = (float*)(ws + 368640);          // 55296
  u16*   BwT  = (u16*)(ws + 423936);            // 294912
  float* nzT  = (float*)(ws + 718848);          // 262144
  u16*   actv = (u16*)(ws + 980992);            // 16777216 (end ~17.8 MB)

  k_labels<<<dim3((BB*HWSZ)/256), dim3(256), 0, stream>>>(seg, lab);
  k_nzT   <<<dim3(BB*16),        dim3(256), 0, stream>>>(noise, nzT);
  k_stats <<<dim3(BB*CC),        dim3(256), 0, stream>>>(x, nzT, nvar, mu, rs);
  k_mm    <<<dim3(BB*FF*8),      dim3(256), 0, stream>>>(codes, fcw, fcb, mm);
  k_p     <<<dim3(BB*FF*8),      dim3(576), 0, stream>>>(mm, cgw, cbw, Pg, Pb);
  k_bw    <<<dim3(576),          dim3(256), 0, stream>>>(sgw, sbw, BwT);
  k_actv  <<<dim3(BB*HH),        dim3(128), 0, stream>>>(mask, ssw, ssb, actv);
  k_spade <<<dim3(BB*HH),        dim3(256), 0, stream>>>(
      actv, BwT, lab, Pg, Pb, x, nzT, nvar, mu, rs,
      cgb, cbb, sgb, sbb, blg, blb, out);
}

// Round 16
// 258.054 us; speedup vs baseline: 15.6169x; 1.0272x over previous
//
#include <hip/hip_runtime.h>
#include <hip/hip_bf16.h>
#include <math.h>

#define BB 4
#define CC 64
#define HH 128
#define WW 128
#define FF 6
#define DD 512
#define NHH 128
#define HWSZ (HH*WW)

typedef unsigned short u16;
typedef __attribute__((ext_vector_type(4))) unsigned short u16x4;
typedef __attribute__((ext_vector_type(8))) short short8;   // 8 bf16 = 4 VGPRs
typedef __attribute__((ext_vector_type(4))) float f32x4;

__device__ inline float b2f(u16 u){
  union { unsigned int i; float f; } v; v.i = ((unsigned int)u) << 16; return v.f;
}
__device__ inline u16 f2b(float f){
  union { float f; unsigned int i; } v; v.f = f;
  unsigned int r = v.i + 0x7fffu + ((v.i >> 16) & 1u);
  return (u16)(r >> 16);
}

// ---------------- K1: labels (blk<256) + noise transpose (blk>=256) ---------
__global__ void k_prep(const float* __restrict__ seg, const float* __restrict__ noise,
                       int* __restrict__ lab, float* __restrict__ nzT){
  int blk = blockIdx.x;
  if (blk < 256){
    int i = blk * 256 + threadIdx.x;
    int b = i >> 14; int hw = i & 16383;
    int l = -1;
    #pragma unroll
    for (int j = 0; j < FF; j++){
      float v = seg[(b*FF + j)*HWSZ + hw];
      if (v != 0.f) l = j;
    }
    lab[i] = l;
  } else {
    __shared__ float tile[32][33];
    int t2 = blk - 256;                 // b*16 + tj*4 + ti
    int b = t2 >> 4, t = t2 & 15;
    int ti = t & 3, tj = t >> 2;
    int h0 = ti*32, w0 = tj*32;
    int tx = threadIdx.x & 31, ty = threadIdx.x >> 5;   // 32x8
    #pragma unroll
    for (int k = 0; k < 4; k++){
      int r = ty + 8*k;
      tile[r][tx] = noise[b*HWSZ + (w0+r)*128 + h0 + tx];
    }
    __syncthreads();
    #pragma unroll
    for (int k = 0; k < 4; k++){
      int r = ty + 8*k;
      nzT[b*HWSZ + (h0+r)*128 + w0 + tx] = tile[tx][r];
    }
  }
}

// ---------------- K2: instance-norm stats (coalesced, float4, shfl) ---------
__global__ void k_stats(const float* __restrict__ x, const float* __restrict__ nzT,
                        const float* __restrict__ nvar, float* __restrict__ mu,
                        float* __restrict__ rs){
  int bc = blockIdx.x; int b = bc >> 6; int c = bc & 63;
  float nv = nvar[c];
  const float4* xp = (const float4*)(x + (size_t)bc * HWSZ);
  const float4* np = (const float4*)(nzT + (size_t)b * HWSZ);
  float s = 0.f, ss = 0.f;
  for (int i = threadIdx.x; i < HWSZ/4; i += 256){
    float4 xv = xp[i], nn = np[i];
    float v0 = xv.x + nn.x*nv, v1 = xv.y + nn.y*nv;
    float v2 = xv.z + nn.z*nv, v3 = xv.w + nn.w*nv;
    s += v0+v1+v2+v3;
    ss += v0*v0 + v1*v1 + v2*v2 + v3*v3;
  }
  #pragma unroll
  for (int off = 32; off; off >>= 1){
    s  += __shfl_down(s, off);
    ss += __shfl_down(ss, off);
  }
  __shared__ float wsum[4], wss[4];
  int wi = threadIdx.x >> 6, lane = threadIdx.x & 63;
  if (lane == 0){ wsum[wi] = s; wss[wi] = ss; }
  __syncthreads();
  if (threadIdx.x == 0){
    float S = wsum[0]+wsum[1]+wsum[2]+wsum[3];
    float SS = wss[0]+wss[1]+wss[2]+wss[3];
    float m = S / (float)HWSZ;
    float var = SS / (float)HWSZ - m*m;
    mu[bc] = m; rs[bc] = rsqrtf(var + 1e-5f);
  }
}

// ---------------- K3: middle_mu, wave-per-o, coalesced, shfl reduce ---------
__global__ __launch_bounds__(256) void k_mm(const float* __restrict__ codes,
                     const float* __restrict__ fcw,
                     const float* __restrict__ fcb, float* __restrict__ mm){
  int blk = blockIdx.x;                 // bf*8 + og
  int og = blk & 7, bf = blk >> 3; int f = bf % FF;
  __shared__ float sc[DD];
  int tid = threadIdx.x;
  for (int i = tid; i < DD; i += 256) sc[i] = codes[bf*DD + i];
  __syncthreads();
  int wi = tid >> 6, lane = tid & 63;
  for (int oo = 0; oo < 16; oo += 2){
    int o1 = og*64 + wi*16 + oo, o2 = o1 + 1;
    const float* w1 = fcw + ((size_t)(f*DD + o1)) * DD;
    const float* w2 = w1 + DD;
    float a1 = 0.f, a2 = 0.f;
    #pragma unroll
    for (int k = 0; k < 8; k++){
      int d = lane + k*64;
      float sv = sc[d];
      a1 += sv * w1[d];
      a2 += sv * w2[d];
    }
    #pragma unroll
    for (int off = 32; off; off >>= 1){
      a1 += __shfl_down(a1, off);
      a2 += __shfl_down(a2, off);
    }
    if (lane == 0){
      mm[bf*DD + o1] = fmaxf(a1 + fcb[f*DD + o1], 0.f);
      mm[bf*DD + o2] = fmaxf(a2 + fcb[f*DD + o2], 0.f);
    }
  }
}

// ---------------- K4a: weight reshape: BwT (spade GEMM B) + WtP (P GEMV) ----
// BwT[j][k], k=tap*128+n, j<64 gamma / j>=64 beta (bf16)
// WtP[mat][tc][d] bf16, tc = t*64+c (576 per mat)  <- w_mat[c][d][t]
__global__ void k_bwp(const float* __restrict__ sgw, const float* __restrict__ sbw,
                      const float* __restrict__ cgw, const float* __restrict__ cbw,
                      u16* __restrict__ BwT, u16* __restrict__ WtP){
  int blk = blockIdx.x;
  if (blk < 576){
    int idx = blk*256 + threadIdx.x;          // 128*1152 = 147456
    int j = idx / 1152, k = idx - j*1152;
    int tap = k >> 7, n = k & 127;
    float v = (j < 64) ? sgw[(j*NHH + n)*9 + tap] : sbw[((j-64)*NHH + n)*9 + tap];
    BwT[idx] = f2b(v);
  } else {
    int idx = (blk - 576)*256 + threadIdx.x;  // 2*576*512 = 589824
    int mat = idx / 294912; int rr = idx - mat*294912;
    int tc = rr >> 9, d = rr & 511;           // tc in 0..575
    int t = tc >> 6, c = tc & 63;             // t in 0..8
    const float* src = mat ? cbw : cgw;
    WtP[idx] = f2b(src[(c*DD + d)*9 + t]);
  }
}

// ---------------- K4b: P[bf][tc] = sum_d mm[bf,d]*WtP[mat][tc][d] -----------
// grid 24*6; block 4 waves; wave handles 48 (mat,tc) tasks, lanes over d
// tasks per bf: 2 mats x 576 tc = 1152 = 6 blocks x 4 waves x 48
__global__ __launch_bounds__(256) void k_p(const float* __restrict__ mm,
                    const u16* __restrict__ WtP,
                    float* __restrict__ Pg, float* __restrict__ Pb){
  int blk = blockIdx.x;
  int q = blk % 6, bf = blk / 6;
  int wid = threadIdx.x >> 6, lane = threadIdx.x & 63;
  const float4* mp = (const float4*)(mm + bf*DD + lane*8);
  float4 m0 = mp[0], m1 = mp[1];
  float mv[8] = {m0.x, m0.y, m0.z, m0.w, m1.x, m1.y, m1.z, m1.w};
  int t0 = q*192 + wid*48;
  for (int j = 0; j < 48; j++){
    int tt = t0 + j;                          // 0..1151
    int mat = tt / 576, tc = tt - mat*576;    // tc in 0..575
    short8 wv = *(const short8*)(WtP + ((size_t)mat*576 + tc)*DD + lane*8);
    float s = 0.f;
    #pragma unroll
    for (int k = 0; k < 8; k++) s += b2f((u16)wv[k]) * mv[k];
    #pragma unroll
    for (int off = 32; off; off >>= 1) s += __shfl_down(s, off);
    if (lane == 0){
      if (mat) Pb[bf*576 + tc] = s; else Pg[bf*576 + tc] = s;
    }
  }
}

// ---------------- K5: actv = relu(conv3x3(mask)), stored NHWC bf16 ----------
__global__ void k_actv(const float* __restrict__ mask, const float* __restrict__ w,
                       const float* __restrict__ bias, u16* __restrict__ actv){
  int bh = blockIdx.x;
  int b = bh >> 7; int h = bh & 127;
  int tw = threadIdx.x;
  float mreg[3][3][3];
  #pragma unroll
  for (int ci = 0; ci < 3; ci++)
    #pragma unroll
    for (int r = 0; r < 3; r++){
      int hh = h - 1 + r;
      #pragma unroll
      for (int dx = 0; dx < 3; dx++){
        int ww2 = tw - 1 + dx;
        mreg[ci][r][dx] = (hh >= 0 && hh < HH && ww2 >= 0 && ww2 < WW)
                          ? mask[((b*3 + ci)*HH + hh)*WW + ww2] : 0.f;
      }
    }
  __shared__ float sw[NHH*27];
  for (int i = threadIdx.x; i < NHH*27; i += 128) sw[i] = w[i];
  __shared__ float sb[NHH];
  sb[threadIdx.x] = bias[threadIdx.x];
  __syncthreads();
  u16* outp = actv + ((size_t)bh * WW + tw) * NHH;
  for (int n0 = 0; n0 < NHH; n0 += 4){
    u16x4 pkt;
    #pragma unroll
    for (int j = 0; j < 4; j++){
      int n = n0 + j;
      float acc = sb[n];
      const float* wn = &sw[n*27];
      #pragma unroll
      for (int ci = 0; ci < 3; ci++)
        #pragma unroll
        for (int r = 0; r < 3; r++)
          #pragma unroll
          for (int dx = 0; dx < 3; dx++)
            acc += mreg[ci][r][dx] * wn[ci*9 + r*3 + dx];
      pkt[j] = f2b(fmaxf(acc, 0.f));
    }
    *(u16x4*)(outp + n0) = pkt;
  }
}

// ---------------- K6: SPADE GEMM (T14 issue-early, A-dbuf) + fused epilogue -
#define LOADT(kt_) { \
  int tap = (kt_) >> 1, n0 = ((kt_) & 1) << 6; \
  int rr = tap/3, dx = tap - rr*3; \
  int h2 = h - 1 + rr; bool hok = (h2>=0) && (h2<HH); \
  _Pragma("unroll") \
  for (int it = 0; it < 4; it++){ \
    int i = it*256 + tid; \
    int pix = i >> 3, cp = i & 7; \
    int w2 = pix - 1 + dx; \
    short8 v = 0; \
    if (hok && w2 >= 0 && w2 < WW) \
      v = *(const short8*)(ab + (((size_t)h2*WW + w2)*NHH + n0 + cp*8)); \
    Ar[it] = v; \
    Br[it] = *(const short8*)(BwT + (size_t)pix*1152 + (kt_)*64 + cp*8); \
  } }

#define WRITET(buf_) { \
  _Pragma("unroll") \
  for (int it = 0; it < 4; it++){ \
    int i = it*256 + tid; \
    int pix = i >> 3, cp = i & 7; \
    *(short8*)&Ash[buf_][pix*72 + cp*8] = Ar[it]; \
    *(short8*)&Bsh[pix*72 + cp*8] = Br[it]; \
  } }

__global__ __launch_bounds__(256, 2) void k_spade(const u16* __restrict__ actv,
    const u16* __restrict__ BwT, const int* __restrict__ lab,
    const float* __restrict__ Pgf, const float* __restrict__ Pbf,
    const float* __restrict__ x, const float* __restrict__ nzT,
    const float* __restrict__ nvar, const float* __restrict__ mu,
    const float* __restrict__ rs,
    const float* __restrict__ cgb, const float* __restrict__ cbb,
    const float* __restrict__ sgb, const float* __restrict__ sbb,
    const float* __restrict__ blg, const float* __restrict__ blb,
    float* __restrict__ out)
{
  int bh = blockIdx.x; int b = bh >> 7; int h = bh & 127;
  __shared__ __align__(16) u16 Ash[2][128*72];   // 2 x 18432 B
  __shared__ __align__(16) u16 Bsh[128*72];      // 18432 B
  __shared__ u16 sP[64*57*2];                    // [c][l*9+t][{g,b}] bf16
  __shared__ int sLab[390];

  int tid = threadIdx.x;
  int wid = tid >> 6, lane = tid & 63;
  int wr = wid >> 1, wc = wid & 1;
  int l15 = lane & 15, lhi = lane >> 4;

  // prologue staging: P table (bf16 pairs) + 3 label rows
  for (int i = tid; i < 3456; i += 256){
    int lt = i >> 6, c = i & 63;
    int f = lt / 9, t = lt - f*9;
    int gidx = (b*FF + f)*576 + t*64 + c;
    sP[(c*57 + lt)*2 + 0] = f2b(Pgf[gidx]);
    sP[(c*57 + lt)*2 + 1] = f2b(Pbf[gidx]);
  }
  for (int i = tid; i < 390; i += 256){
    int r = i / 130, ww2 = i % 130;
    int hh = h - 1 + r, w2 = ww2 - 1;
    sLab[i] = (hh >= 0 && hh < HH && w2 >= 0 && w2 < WW)
              ? lab[b*HWSZ + hh*WW + w2] : -1;
  }

  f32x4 acc[4][4];
  #pragma unroll
  for (int mi = 0; mi < 4; mi++)
    #pragma unroll
    for (int ni = 0; ni < 4; ni++) acc[mi][ni] = 0.f;

  const u16* ab = actv + (size_t)b * HWSZ * NHH;
  short8 Ar[4], Br[4];

  LOADT(0)
  WRITET(0)
  __syncthreads();

  int cur = 0;
  for (int kt = 0; kt < 18; kt++){
    if (kt < 17) LOADT(kt+1)                     // issue-early (T14)
    __builtin_amdgcn_sched_barrier(0);           // pin loads before compute
    short8 af[4][2], bfr[2][4];
    #pragma unroll
    for (int mi = 0; mi < 4; mi++)
      #pragma unroll
      for (int ks = 0; ks < 2; ks++)
        af[mi][ks] = *(const short8*)&Ash[cur][(wr*64 + mi*16 + l15)*72 + ks*32 + lhi*8];
    #pragma unroll
    for (int ks = 0; ks < 2; ks++)
      #pragma unroll
      for (int ni = 0; ni < 4; ni++)
        bfr[ks][ni] = *(const short8*)&Bsh[(wc*64 + ni*16 + l15)*72 + ks*32 + lhi*8];
    #pragma unroll
    for (int mi = 0; mi < 4; mi++)
      #pragma unroll
      for (int ni = 0; ni < 4; ni++)
        #pragma unroll
        for (int ks = 0; ks < 2; ks++)
          acc[mi][ni] = __builtin_amdgcn_mfma_f32_16x16x32_bf16(
              af[mi][ks], bfr[ks][ni], acc[mi][ni], 0, 0, 0);
    __syncthreads();                             // all reads of Ash[cur]/Bsh done
    if (kt < 17) WRITET(cur^1)                   // write-late; vmcnt waited by compiler
    __syncthreads();                             // writes visible
    cur ^= 1;
  }

  // ---- epilogue phase 1: acc -> LDS spGB[j][132] (bf16), reuses Ash region -
  u16* spGB = &Ash[0][0];                        // 33792 B <= 36864 B
  #pragma unroll
  for (int mi = 0; mi < 4; mi++){
    int w0 = wr*64 + mi*16 + lhi*4;
    #pragma unroll
    for (int ni = 0; ni < 4; ni++){
      int j = wc*64 + ni*16 + l15;
      u16x4 pkt;
      #pragma unroll
      for (int q = 0; q < 4; q++) pkt[q] = f2b(acc[mi][ni][q]);
      *(u16x4*)&spGB[j*132 + w0] = pkt;
    }
  }
  __syncthreads();

  // ---- epilogue phase 2: region gather + norm + blend, write out ----
  float sga = 1.f / (1.f + expf(-blg[0]));
  float sba = 1.f / (1.f + expf(-blb[0]));
  int w = tid & 127, chalf = tid >> 7;
  float nzv = nzT[b*HWSZ + h*128 + w];
  int lt9[9];
  #pragma unroll
  for (int t = 0; t < 9; t++){
    int r = t/3, dx = t - r*3;
    lt9[t] = sLab[r*130 + w + dx];
  }
  for (int it = 0; it < 32; it++){
    int c = it*2 + chalf;
    int bc = b*CC + c;
    float g  = b2f(spGB[c*132 + w])        + sgb[c];
    float bt = b2f(spGB[(64 + c)*132 + w]) + sbb[c];
    float gA = cgb[c], bA = cbb[c];
    #pragma unroll
    for (int t = 0; t < 9; t++){
      int l = lt9[t];
      if (l >= 0){
        unsigned pr = *(const unsigned*)&sP[(c*57 + l*9 + t)*2];
        gA += b2f((u16)(pr & 0xffffu));
        bA += b2f((u16)(pr >> 16));
      }
    }
    float gf  = sga*gA + (1.f - sga)*g;
    float bfv = sba*bA + (1.f - sba)*bt;
    size_t idx = (size_t)bc*HWSZ + h*128 + w;
    float xn = x[idx] + nzv * nvar[c];
    float xnorm = (xn - mu[bc]) * rs[bc];
    out[idx] = xnorm * (1.f + gf) + bfv;
  }
}

extern "C" void kernel_launch(void* const* d_in, const int* in_sizes, int n_in,
                              void* d_out, int out_size, void* d_ws, size_t ws_size,
                              hipStream_t stream){
  const float* x     = (const float*)d_in[0];
  const float* seg   = (const float*)d_in[1];
  const float* mask  = (const float*)d_in[2];
  const float* codes = (const float*)d_in[3];
  const float* noise = (const float*)d_in[4];
  const float* nvar  = (const float*)d_in[5];
  const float* fcw   = (const float*)d_in[6];
  const float* fcb   = (const float*)d_in[7];
  const float* cgw   = (const float*)d_in[8];
  const float* cgb   = (const float*)d_in[9];
  const float* cbw   = (const float*)d_in[10];
  const float* cbb   = (const float*)d_in[11];
  const float* ssw   = (const float*)d_in[12];
  const float* ssb   = (const float*)d_in[13];
  const float* sgw   = (const float*)d_in[14];
  const float* sgb   = (const float*)d_in[15];
  const float* sbw   = (const float*)d_in[16];
  const float* sbb   = (const float*)d_in[17];
  const float* blg   = (const float*)d_in[18];
  const float* blb   = (const float*)d_in[19];
  float* out = (float*)d_out;

  char* ws = (char*)d_ws;
  int*   lab  = (int*)ws;                       // 262144 B
  float* mu   = (float*)(ws + 262144);          // 1024
  float* rs   = (float*)(ws + 263168);          // 1024
  float* mm   = (float*)(ws + 264192);          // 49152
  float* Pg   = (float*)(ws + 313344);          // 55296
  float* Pb   = (float*)(ws + 368640);          // 55296
  u16*   BwT  = (u16*)(ws + 423936);            // 294912
  float* nzT  = (float*)(ws + 718848);          // 262144
  u16*   WtP  = (u16*)(ws + 980992);            // 1179648  (2*576*512 bf16)
  u16*   actv = (u16*)(ws + 2160640);           // 16777216 (end ~18.9 MB)

  k_prep  <<<dim3(320),          dim3(256), 0, stream>>>(seg, noise, lab, nzT);
  k_stats <<<dim3(BB*CC),        dim3(256), 0, stream>>>(x, nzT, nvar, mu, rs);
  k_mm    <<<dim3(BB*FF*8),      dim3(256), 0, stream>>>(codes, fcw, fcb, mm);
  k_bwp   <<<dim3(2880),         dim3(256), 0, stream>>>(sgw, sbw, cgw, cbw, BwT, WtP);
  k_p     <<<dim3(BB*FF*6),      dim3(256), 0, stream>>>(mm, WtP, Pg, Pb);
  k_actv  <<<dim3(BB*HH),        dim3(128), 0, stream>>>(mask, ssw, ssb, actv);
  k_spade <<<dim3(BB*HH),        dim3(256), 0, stream>>>(
      actv, BwT, lab, Pg, Pb, x, nzT, nvar, mu, rs,
      cgb, cbb, sgb, sbb, blg, blb, out);
}